// Round 16
// baseline (103.008 us; speedup 1.0000x reference)
//
#include <hip/hip_runtime.h>
#include <math.h>

// NGRU via MFMA, R16 = barrier-free wave-autonomous GRU.
// Only layer 1 of the 2 parallel GRU layers contributes (reference returns
// h_final[-1]); layer 0 is skipped.
//
// Shapes: x (64,48,256,64) f32; Wih/Whh (2,192,64); bih/bhh (2,192).
// rows = B*N = 16384 independent GRU sequences, T=48, H=64.
//
// DIAGNOSIS (R9..R15): the per-step __syncthreads phase-locks all waves on
// a CU -> LDS, MFMA, VALU/TRANS phases run SEQUENTIALLY (step = sum ~3400
// cyc). Every forced de-phasing attempt failed.
// FIX: re-tile so ONE WAVE owns 16 rows x ALL 64 columns. The wave produces
// the complete h(t) for exactly the rows it consumes at t+1 -> the cross-
// wave h dependency vanishes. h redistribution (C-layout -> A-layout
// transpose) goes through the wave's PRIVATE LDS buffer; the per-wave
// in-order LDS pipe makes write->read safe with NO barrier. Waves free-run
// and de-phase naturally; different waves' MFMA/VALU/LDS phases overlap.
//
// Structure: 256 blocks x 256 threads (4 autonomous waves, no sync at all).
// 16 rows/wave -> 1024 waves = 1 wave/SIMD, so amdgpu_waves_per_eu(1,1)
// grants the full ~512-VGPR budget for B-frags(192) + acc(64) + rest ~345
// (m08: no spill through 450). Per wave/step: 4 ds_read_b128 + 48 MFMA
// (16 independent chains) + 16-h epilogue + 16 ds_write_b16 + x stage.
// Per-CU totals identical to R9; the sequential phase-sum is replaced by
// cross-wave statistical overlap.
//
// fp16 single-product MFMA (R9-verified: matmul precision is not the error
// term). Bias added in epilogue (reorder vs R9 ~1 ulp f32, invisible).
// x(t+1) loads are UNCONDITIONAL with clamped index (R10/R14 lesson: the
// if(hasNext) guard lets the compiler merge load-block into use-block and
// sink the prefetch).

#define TT 48
#define HH 64
#define GG 192
#define NN 256
#define RPW 16          // rows per wave
#define NTHREADS 256    // 4 autonomous waves per block
#define AK 136          // A row stride in halfs (128 + 8 pad)
#define WBUF (RPW*AK)   // 2176 halfs = 4352 B per wave-private buffer

typedef _Float16 h8 __attribute__((ext_vector_type(8)));   // 8 fp16 (4 VGPRs)
typedef __attribute__((ext_vector_type(4))) float f32x4;   // MFMA accum
typedef __attribute__((ext_vector_type(4))) unsigned u32x4;

__device__ __forceinline__ float sigm(float v) {
    return __builtin_amdgcn_rcpf(1.f + __expf(-v));
}
__device__ __forceinline__ float tanh_f(float v) {
    float a = fabsf(v);
    float e = __expf(2.f * a);
    float t = 1.f - 2.f * __builtin_amdgcn_rcpf(e + 1.f);
    return v < 0.f ? -t : t;
}
// pack 2 f32 -> dword of 2 fp16 (RNE)
__device__ __forceinline__ unsigned pkh2(float a, float b) {
    union { _Float16 h[2]; unsigned u; } c;
    c.h[0] = (_Float16)a; c.h[1] = (_Float16)b;
    return c.u;
}

#define MF(A, B, C) __builtin_amdgcn_mfma_f32_16x16x32_f16(A, B, C, 0, 0, 0)

__global__ __launch_bounds__(NTHREADS)
__attribute__((amdgpu_waves_per_eu(1, 1)))
void ngru_mfma16(const float* __restrict__ x,
                 const float* __restrict__ Wih,
                 const float* __restrict__ Whh,
                 const float* __restrict__ bih,
                 const float* __restrict__ bhh,
                 float* __restrict__ out)
{
    extern __shared__ __align__(16) _Float16 lds_h[];  // 4 x WBUF halfs

    const int tid  = threadIdx.x;
    const int lane = tid & 63;
    const int wv   = tid >> 6;          // wave 0..3 (fully autonomous)
    const int c0   = lane & 15;         // A row index / C col-within-tile
    const int rq   = lane >> 4;         // quarter-wave
    _Float16* buf  = lds_h + wv * WBUF; // private [16][AK]: cols 0..63 x, 64..127 h

    const int grow0 = blockIdx.x * 64 + wv * RPW;   // this wave's 16 rows
    const int bb    = grow0 / NN;       // 16-row groups never straddle a batch
    const int n0    = grow0 % NN;

    const float* Wi = Wih + GG * HH;    // layer 1
    const float* Wh = Whh + GG * HH;

    // ---- B fragments (fp16) in registers: full j range (4 j-tiles) ----
    // Bx[g][jt][kt]: Wi gate g (0=r,1=z,2=n), pairs with A[kt] (x cols)
    // Bh[g][jt][kt]: Wh gate g,             pairs with A[2+kt] (h cols)
    h8 Bx[3][4][2], Bh[3][4][2];
    #pragma unroll
    for (int g = 0; g < 3; ++g)
        #pragma unroll
        for (int jt = 0; jt < 4; ++jt)
            #pragma unroll
            for (int kt = 0; kt < 2; ++kt) {
                const int jrow = g * 64 + jt * 16 + c0;
                const float* si = Wi + jrow * HH + kt * 32 + rq * 8;
                const float* sh = Wh + jrow * HH + kt * 32 + rq * 8;
                h8 fi, fh;
                #pragma unroll
                for (int q = 0; q < 8; ++q) {
                    fi[q] = (_Float16)si[q];
                    fh[q] = (_Float16)sh[q];
                }
                Bx[g][jt][kt] = fi;
                Bh[g][jt][kt] = fh;
            }

    // ---- biases per j-tile (scalar per lane; added in epilogue) ----
    float brz[4], bzz[4], bin_[4], bhn_[4];
    #pragma unroll
    for (int jt = 0; jt < 4; ++jt) {
        const int jj = jt * 16 + c0;
        brz[jt]  = bih[GG + jj]       + bhh[GG + jj];
        bzz[jt]  = bih[GG + 64 + jj]  + bhh[GG + 64 + jj];
        bin_[jt] = bih[GG + 128 + jj];
        bhn_[jt] = bhh[GG + 128 + jj];
    }

    // ---- staging geometry: lane covers row=lane>>2, cols (lane&3)*16..+16 ----
    const int srow = lane >> 2;          // 0..15
    const int scol = (lane & 3) * 16;    // 0,16,32,48

    // ---- init: zero h half, stage x(0) (wave-private; in-order LDS) ----
    {
        u32x4 z = {0u, 0u, 0u, 0u};
        *(u32x4*)(buf + srow * AK + 64 + scol)     = z;
        *(u32x4*)(buf + srow * AK + 64 + scol + 8) = z;

        const float* xs = x + ((size_t)(bb * TT) * NN + n0 + srow) * HH + scol;
        float4 q0 = *(const float4*)xs;
        float4 q1 = *(const float4*)(xs + 4);
        float4 q2 = *(const float4*)(xs + 8);
        float4 q3 = *(const float4*)(xs + 12);
        u32x4 w0 = {pkh2(q0.x,q0.y), pkh2(q0.z,q0.w),
                    pkh2(q1.x,q1.y), pkh2(q1.z,q1.w)};
        u32x4 w1 = {pkh2(q2.x,q2.y), pkh2(q2.z,q2.w),
                    pkh2(q3.x,q3.y), pkh2(q3.z,q3.w)};
        *(u32x4*)(buf + srow * AK + scol)     = w0;
        *(u32x4*)(buf + srow * AK + scol + 8) = w1;
    }

    float hreg[4][4];
    #pragma unroll
    for (int jt = 0; jt < 4; ++jt)
        #pragma unroll
        for (int r = 0; r < 4; ++r) hreg[jt][r] = 0.f;

    const f32x4 Z4 = {0.f, 0.f, 0.f, 0.f};

    // NO barrier anywhere: all LDS deps are wave-private, pipe is in-order.
    #pragma unroll 1
    for (int t = 0; t < TT; ++t) {
        // ---- A-fragment reads (4 x ds_read_b128; x kt0,1 / h kt2,3) ----
        h8 A0 = *(const h8*)(buf + c0 * AK + 0  + rq * 8);
        h8 A1 = *(const h8*)(buf + c0 * AK + 32 + rq * 8);
        h8 A2 = *(const h8*)(buf + c0 * AK + 64 + rq * 8);
        h8 A3 = *(const h8*)(buf + c0 * AK + 96 + rq * 8);

        // ---- x(t+1) loads, UNCONDITIONAL (clamped; avoids sink-merge) ----
        const int tn = (t + 1 < TT) ? t + 1 : t;
        const float* xs =
            x + ((size_t)(bb * TT + tn) * NN + n0 + srow) * HH + scol;
        float4 q0 = *(const float4*)xs;
        float4 q1 = *(const float4*)(xs + 4);
        float4 q2 = *(const float4*)(xs + 8);
        float4 q3 = *(const float4*)(xs + 12);

        // ---- 48 MFMAs: 16 independent chains (4 j-tiles x 4 gates) ----
        f32x4 ar[4], az[4], ai[4], ah[4];
        #pragma unroll
        for (int jt = 0; jt < 4; ++jt) {
            ar[jt] = MF(A0, Bx[0][jt][0], Z4);
            ar[jt] = MF(A1, Bx[0][jt][1], ar[jt]);
            ar[jt] = MF(A2, Bh[0][jt][0], ar[jt]);
            ar[jt] = MF(A3, Bh[0][jt][1], ar[jt]);
            az[jt] = MF(A0, Bx[1][jt][0], Z4);
            az[jt] = MF(A1, Bx[1][jt][1], az[jt]);
            az[jt] = MF(A2, Bh[1][jt][0], az[jt]);
            az[jt] = MF(A3, Bh[1][jt][1], az[jt]);
            ai[jt] = MF(A0, Bx[2][jt][0], Z4);
            ai[jt] = MF(A1, Bx[2][jt][1], ai[jt]);
            ah[jt] = MF(A2, Bh[2][jt][0], Z4);
            ah[jt] = MF(A3, Bh[2][jt][1], ah[jt]);
        }

        // ---- epilogue: 16 h per lane; write h(t) into own buffer ----
        #pragma unroll
        for (int jt = 0; jt < 4; ++jt) {
            #pragma unroll
            for (int r = 0; r < 4; ++r) {
                float sr  = ar[jt][r] + brz[jt];
                float sz  = az[jt][r] + bzz[jt];
                float gin = ai[jt][r] + bin_[jt];
                float ghn = ah[jt][r] + bhn_[jt];
                float rg = sigm(sr);
                float zg = sigm(sz);
                float ng = tanh_f(fmaf(rg, ghn, gin));
                float hn = fmaf(zg, hreg[jt][r] - ng, ng);   // (1-z)n + z h
                hreg[jt][r] = hn;
                buf[(rq * 4 + r) * AK + 64 + jt * 16 + c0] = (_Float16)hn;
            }
        }

        // ---- stage x(t+1) into own buffer (in-order after this step's reads)
        u32x4 w0 = {pkh2(q0.x,q0.y), pkh2(q0.z,q0.w),
                    pkh2(q1.x,q1.y), pkh2(q1.z,q1.w)};
        u32x4 w1 = {pkh2(q2.x,q2.y), pkh2(q2.z,q2.w),
                    pkh2(q3.x,q3.y), pkh2(q3.z,q3.w)};
        *(u32x4*)(buf + srow * AK + scol)     = w0;
        *(u32x4*)(buf + srow * AK + scol + 8) = w1;
    }

    // ---- output: rows rq*4+r, cols jt*16+c0 ----
    #pragma unroll
    for (int jt = 0; jt < 4; ++jt)
        #pragma unroll
        for (int r = 0; r < 4; ++r)
            out[(size_t)(grow0 + rq * 4 + r) * HH + jt * 16 + c0] =
                hreg[jt][r];
}

extern "C" void kernel_launch(void* const* d_in, const int* in_sizes, int n_in,
                              void* d_out, int out_size, void* d_ws, size_t ws_size,
                              hipStream_t stream) {
    const float* x   = (const float*)d_in[0];
    const float* Wih = (const float*)d_in[1];
    const float* Whh = (const float*)d_in[2];
    const float* bih = (const float*)d_in[3];
    const float* bhh = (const float*)d_in[4];
    float* out = (float*)d_out;

    const int lds_bytes = 4 * WBUF * (int)sizeof(_Float16);   // 17,408 B
    (void)hipFuncSetAttribute((const void*)ngru_mfma16,
                        hipFuncAttributeMaxDynamicSharedMemorySize, lds_bytes);

    dim3 grid(16384 / 64);      // 256 blocks, 1 per CU, 4 waves = 1/SIMD
    dim3 block(NTHREADS);
    ngru_mfma16<<<grid, block, lds_bytes, stream>>>(x, Wih, Whh, bih, bhh, out);
}

// Round 17
// 70.708 us; speedup vs baseline: 1.4568x; 1.4568x over previous
//
#include <hip/hip_runtime.h>
#include <math.h>

// NGRU via MFMA, R17 = R9 shell with j-doubled waves (16 rows x 32 cols).
// Only layer 1 of the 2 parallel GRU layers contributes (reference returns
// h_final[-1]); layer 0 is skipped.
//
// Shapes: x (64,48,256,64) f32; Wih/Whh (2,192,64); bih/bhh (2,192).
// rows = B*N = 16384 independent GRU sequences, T=48, H=64.
//
// PIPE ACCOUNTING (R9, measured 3400 cyc/step/CU): LDS is the heaviest
// pipe (~1230 cyc: 64 ds_read_b128 A-reads + h/x writes); MFMA ~233/SIMD;
// VALU+TRANS ~880/SIMD. A-read traffic is tiling redundancy: R9's 4 j-split
// waves each read the SAME 32x128 A-tile (32 KB/block/step).
// R17: wave = 16 rows x 32 j-cols (mq = wv>>1 row half, jh = wv&1 col
// half). A-read per wave = 4 KB (4 b128) -> 16 KB/block/step, HALF of R9.
// B-fragments: 2 jt-tiles x 12 slots = 96 VGPRs = R5's proven sustained
// budget (VGPR ~116-140 total; the allocator wall at ~130+ killed R4/R7/
// R8/R10/R14/R16 — this stays inside the envelope).
// MFMA/wave unchanged (24), epilogue unchanged (8 h/thread), same shell:
// 512 blocks x 256 threads, 32 rows/block, 2 blocks/CU, ONE barrier/step.
// Chain order per output element exactly R9 -> bit-identical numerics.
//
// A = [x_t | h_{t-1}] fp16 [32][AK=136], ping-ponged. fp16 single-product
// MFMA (R9-verified: matmul precision is not the error term).
// waves_per_eu(2,2): full VGPR budget at the grid-fixed residency.

#define TT 48
#define HH 64
#define GG 192
#define NN 256
#define RPB 32          // rows per block
#define NTHREADS 256    // 4 waves
#define AK 136          // A row stride in halfs (128 + 8 pad; 16B-aligned rows)
#define HBUF (RPB*AK)   // halfs per A buffer (4352)

typedef _Float16 h8 __attribute__((ext_vector_type(8)));   // 8 fp16 (4 VGPRs)
typedef __attribute__((ext_vector_type(4))) float f32x4;   // MFMA accum
typedef __attribute__((ext_vector_type(4))) unsigned u32x4;

__device__ __forceinline__ float sigm(float v) {
    return __builtin_amdgcn_rcpf(1.f + __expf(-v));
}
__device__ __forceinline__ float tanh_f(float v) {
    float a = fabsf(v);
    float e = __expf(2.f * a);
    float t = 1.f - 2.f * __builtin_amdgcn_rcpf(e + 1.f);
    return v < 0.f ? -t : t;
}
// pack 2 f32 -> dword of 2 fp16 (RNE)
__device__ __forceinline__ unsigned pkh2(float a, float b) {
    union { _Float16 h[2]; unsigned u; } c;
    c.h[0] = (_Float16)a; c.h[1] = (_Float16)b;
    return c.u;
}

#define MF(A, B, C) __builtin_amdgcn_mfma_f32_16x16x32_f16(A, B, C, 0, 0, 0)

__global__ __launch_bounds__(NTHREADS)
__attribute__((amdgpu_waves_per_eu(2, 2)))
void ngru_mfma17(const float* __restrict__ x,
                 const float* __restrict__ Wih,
                 const float* __restrict__ Whh,
                 const float* __restrict__ bih,
                 const float* __restrict__ bhh,
                 float* __restrict__ out)
{
    extern __shared__ __align__(16) _Float16 lds_h[];  // 2 x HBUF halfs

    const int tid  = threadIdx.x;
    const int lane = tid & 63;
    const int wv   = tid >> 6;          // wave 0..3
    const int mq   = wv >> 1;           // row half: rows [16mq, 16mq+16)
    const int jh   = wv & 1;            // col half: cols [32jh, 32jh+32)
    const int c0   = lane & 15;         // A row within m-tile / C col in tile
    const int rq   = lane >> 4;         // quarter-wave
    const int rbase = mq * 16;

    const int grow0 = blockIdx.x * RPB;
    const int bb    = grow0 / NN;
    const int n0    = grow0 % NN;

    const float* Wi = Wih + GG * HH;    // layer 1
    const float* Wh = Whh + GG * HH;

    // ---- B fragments (fp16): 2 jt-tiles x 12 kt-slots = 96 VGPRs ----
    // per jt, slot layout (R9): r -> 0..3 (kt0,1 = Wi; kt2,3 = Wh);
    // z -> 4..7; gin -> 8,9 (Wi, A kt0,1); ghn -> 10,11 (Wh, A kt2,3).
    h8 Bf[2][12];
    #pragma unroll
    for (int jt = 0; jt < 2; ++jt) {
        const int jj = jh * 32 + jt * 16 + c0;
        #pragma unroll
        for (int g = 0; g < 4; ++g) {
            const int ktlo = (g == 3) ? 2 : 0;
            const int kthi = (g == 2) ? 2 : 4;
            #pragma unroll
            for (int kt = ktlo; kt < kthi; ++kt) {
                const int slot = (g < 2) ? g * 4 + kt
                                         : 8 + (g - 2) * 2 + (kt & 1);
                const bool isWi = (kt < 2);
                const int gbase = (g >= 2) ? 2 : g;
                const float* src = (isWi ? Wi : Wh)
                                 + (gbase * 64 + jj) * HH + (kt & 1) * 32 + rq * 8;
                h8 f;
                #pragma unroll
                for (int q = 0; q < 8; ++q) f[q] = (_Float16)src[q];
                Bf[jt][slot] = f;
            }
        }
    }

    // ---- biases per jt (r/z pre-summed; n biases separate) ----
    float brz[2], bzz[2], bin_[2], bhn_[2];
    #pragma unroll
    for (int jt = 0; jt < 2; ++jt) {
        const int jj = jh * 32 + jt * 16 + c0;
        brz[jt]  = bih[GG + jj]      + bhh[GG + jj];
        bzz[jt]  = bih[GG + 64 + jj] + bhh[GG + 64 + jj];
        bin_[jt] = bih[GG + 128 + jj];
        bhn_[jt] = bhh[GG + 128 + jj];
    }

    // ---- init buf0: zero h region, stage x_0 ----
    const int xrow = tid >> 3;          // 0..31
    const int xkc  = (tid & 7) * 8;     // half offset 0,8,...,56
    {
        *(u32x4*)(lds_h + xrow * AK + 64 + xkc) = (u32x4){0u, 0u, 0u, 0u};

        const float* xsrc = x + ((size_t)(bb * TT) * NN + n0 + xrow) * HH + xkc;
        float4 p0 = *(const float4*)xsrc;
        float4 p1 = *(const float4*)(xsrc + 4);
        u32x4 w = {pkh2(p0.x, p0.y), pkh2(p0.z, p0.w),
                   pkh2(p1.x, p1.y), pkh2(p1.z, p1.w)};
        *(u32x4*)(lds_h + xrow * AK + xkc) = w;
    }

    float hreg[2][4];
    #pragma unroll
    for (int jt = 0; jt < 2; ++jt)
        #pragma unroll
        for (int r = 0; r < 4; ++r) hreg[jt][r] = 0.f;

    __syncthreads();   // buf0 ready for t=0

    for (int t = 0; t < TT; ++t) {
        _Float16* cur = lds_h + (t & 1) * HBUF;
        _Float16* nxt = lds_h + ((t & 1) ^ 1) * HBUF;
        const bool hasNext = (t + 1 < TT);

        // prefetch x_{t+1} (HBM/L3 latency hides under the MFMA phase)
        float4 p0, p1;
        if (hasNext) {
            const float* xsrc =
                x + ((size_t)(bb * TT + t + 1) * NN + n0 + xrow) * HH + xkc;
            p0 = *(const float4*)xsrc;
            p1 = *(const float4*)(xsrc + 4);
        }

        // ===== A reads: ONLY this wave's 16 rows (4 x ds_read_b128) =====
        const _Float16* ab = cur + (rbase + c0) * AK + rq * 8;
        h8 A0 = *(const h8*)(ab);
        h8 A1 = *(const h8*)(ab + 32);
        h8 A2 = *(const h8*)(ab + 64);
        h8 A3 = *(const h8*)(ab + 96);

        // acc preloaded with biases (constant across the 4 C-regs of a tile)
        f32x4 acc[2][4];
        #pragma unroll
        for (int jt = 0; jt < 2; ++jt) {
            acc[jt][0] = (f32x4){brz[jt],  brz[jt],  brz[jt],  brz[jt] };
            acc[jt][1] = (f32x4){bzz[jt],  bzz[jt],  bzz[jt],  bzz[jt] };
            acc[jt][2] = (f32x4){bin_[jt], bin_[jt], bin_[jt], bin_[jt]};
            acc[jt][3] = (f32x4){bhn_[jt], bhn_[jt], bhn_[jt], bhn_[jt]};
        }

        // ===== MFMA: 2 jt-tiles x 12, kt-ascending per acc (R9 order) =====
        __builtin_amdgcn_s_setprio(1);
        #pragma unroll
        for (int jt = 0; jt < 2; ++jt) {
            acc[jt][0] = MF(A0, Bf[jt][0], acc[jt][0]);
            acc[jt][0] = MF(A1, Bf[jt][1], acc[jt][0]);
            acc[jt][0] = MF(A2, Bf[jt][2], acc[jt][0]);
            acc[jt][0] = MF(A3, Bf[jt][3], acc[jt][0]);
            acc[jt][1] = MF(A0, Bf[jt][4], acc[jt][1]);
            acc[jt][1] = MF(A1, Bf[jt][5], acc[jt][1]);
            acc[jt][1] = MF(A2, Bf[jt][6], acc[jt][1]);
            acc[jt][1] = MF(A3, Bf[jt][7], acc[jt][1]);
            acc[jt][2] = MF(A0, Bf[jt][8], acc[jt][2]);
            acc[jt][2] = MF(A1, Bf[jt][9], acc[jt][2]);
            acc[jt][3] = MF(A2, Bf[jt][10], acc[jt][3]);
            acc[jt][3] = MF(A3, Bf[jt][11], acc[jt][3]);
        }
        __builtin_amdgcn_s_setprio(0);

        // ===== epilogue: register-local gates; h -> nxt buffer =====
        #pragma unroll
        for (int jt = 0; jt < 2; ++jt) {
            const int col = 64 + jh * 32 + jt * 16 + c0;
            #pragma unroll
            for (int r = 0; r < 4; ++r) {
                const int row = rbase + rq * 4 + r;
                float rg = sigm(acc[jt][0][r]);
                float zg = sigm(acc[jt][1][r]);
                float ng = tanh_f(fmaf(rg, acc[jt][3][r], acc[jt][2][r]));
                float hn = fmaf(zg, hreg[jt][r] - ng, ng);   // (1-z)n + z h
                hreg[jt][r] = hn;
                if (hasNext)
                    nxt[row * AK + col] = (_Float16)hn;   // ds_write_b16
            }
        }

        if (hasNext) {
            u32x4 w = {pkh2(p0.x, p0.y), pkh2(p0.z, p0.w),
                       pkh2(p1.x, p1.y), pkh2(p1.z, p1.w)};
            *(u32x4*)(nxt + xrow * AK + xkc) = w;
            __syncthreads();   // nxt (h_t + x_{t+1}) ready for step t+1
        }
    }

    #pragma unroll
    for (int jt = 0; jt < 2; ++jt)
        #pragma unroll
        for (int r = 0; r < 4; ++r)
            out[(size_t)(grow0 + rbase + rq * 4 + r) * HH
                + jh * 32 + jt * 16 + c0] = hreg[jt][r];
}

extern "C" void kernel_launch(void* const* d_in, const int* in_sizes, int n_in,
                              void* d_out, int out_size, void* d_ws, size_t ws_size,
                              hipStream_t stream) {
    const float* x   = (const float*)d_in[0];
    const float* Wih = (const float*)d_in[1];
    const float* Whh = (const float*)d_in[2];
    const float* bih = (const float*)d_in[3];
    const float* bhh = (const float*)d_in[4];
    float* out = (float*)d_out;

    const int lds_bytes = 2 * HBUF * (int)sizeof(_Float16);   // 17,408 B
    (void)hipFuncSetAttribute((const void*)ngru_mfma17,
                        hipFuncAttributeMaxDynamicSharedMemorySize, lds_bytes);

    dim3 grid(16384 / RPB);     // 512 blocks, 2 per CU
    dim3 block(NTHREADS);
    ngru_mfma17<<<grid, block, lds_bytes, stream>>>(x, Wih, Whh, bih, bhh, out);
}